// Round 11
// baseline (237.748 us; speedup 1.0000x reference)
//
#include <hip/hip_runtime.h>
#include <hip/hip_fp16.h>

#define N_NODES 100000
#define N_EDGES 3200000
#define E_TOT   (N_EDGES + N_NODES)   // 3.3M edges incl self-loops
#define IN_C 128
#define HID  16
#define OUTC 5
#define NEG_SLOPE 0.2f

#define NBKT 782        // buckets of 128 dsts: b = dst >> 7
#define CAP  5120       // per-bucket pairs capacity (mean 4220, +~13 sigma)
#define HCAP 2816       // half-bucket lcsr capacity (mean 2110, +~15 sigma)
#define P_TILE 8192     // 10.5 edges/bucket/tile -> pairs write-combining restored
#define PART_TILES ((E_TOT + P_TILE - 1) / P_TILE)  // 403
#define NT 64                                        // nodes per projection tile
#define PROJ_TILES ((N_NODES + NT - 1) / NT)         // 1563
#define XH 136          // sXh row stride in halves (272B rows, 2-way alias = free)
#define XPADW 132       // sWt row stride in floats

__device__ __forceinline__ float pk_half2(float a, float b) {
    __half2 h = __halves2half2(__float2half(a), __float2half(b));
    return *(float*)&h;
}
__device__ __forceinline__ float2 unpk_half2(float v) {
    return __half22float2(*(__half2*)&v);
}

// ============ fused: edge partition (blocks 0..402) + layer-1 projection ============
__global__ __launch_bounds__(256) void partproj_k(
    const int* __restrict__ ei, int* __restrict__ gcnt, unsigned* __restrict__ pairs,
    const float* __restrict__ x, const float* __restrict__ W1,
    const float* __restrict__ att_d,
    __half* __restrict__ h1f, float* __restrict__ a_dst) {
    __shared__ __align__(16) char smem[55408];
    int t = threadIdx.x;
    if (blockIdx.x < PART_TILES) {
        // ---- partition path: staged vbuf/bbuf (L2 write-combining on pairs stores) ----
        unsigned* vbuf       = (unsigned*)smem;                  // 32768 B
        unsigned short* bbuf = (unsigned short*)(smem + 32768);  // 16384 B
        int* hist            = (int*)(smem + 49152);             //  3128 B
        int* cur             = (int*)(smem + 52280);             //  3128 B
        for (int i = t; i < NBKT; i += 256) hist[i] = 0;
        __syncthreads();
        int base = blockIdx.x * P_TILE;
        int lim = E_TOT - base; if (lim > P_TILE) lim = P_TILE;
        for (int i = t; i < lim; i += 256) {
            int e = base + i;
            int s, d;
            if (e < N_EDGES) { s = ei[e]; d = ei[N_EDGES + e]; }
            else             { s = e - N_EDGES; d = s; }
            int b = d >> 7;
            vbuf[i] = ((unsigned)s << 7) | (unsigned)(d & 127);
            bbuf[i] = (unsigned short)b;
            atomicAdd(&hist[b], 1);
        }
        __syncthreads();
        for (int i = t; i < NBKT; i += 256) {
            int h = hist[i];
            cur[i] = h ? atomicAdd(&gcnt[i], h) : 0;   // reserve [cur, cur+h)
        }
        __syncthreads();
        for (int i = t; i < lim; i += 256) {
            int b = bbuf[i];
            int p = atomicAdd(&cur[b], 1);
            if (p >= 0 && p < CAP) pairs[(size_t)b * CAP + p] = vbuf[i];
        }
    } else {
        // ---------- projection path: h1 = x@W1, 2x2 register tile, fp16 x-tile ----------
        __half* sXh = (__half*)smem;           // 64 x 136 halves = 17408 B
        float*  sWt = (float*)(smem + 17408);  // 16 x 132 floats =  8448 B
        int bid = blockIdx.x - PART_TILES;
        int node0 = bid * NT;
        for (int i = t; i < IN_C * HID; i += 256) {
            int k = i >> 4, c = i & 15;
            sWt[c * XPADW + k] = W1[i];
        }
        const float4* x4 = (const float4*)x;
        for (int i = t; i < NT * 32; i += 256) {     // 2048 float4
            int r = i >> 5, c4 = i & 31;
            int node = node0 + r;
            float4 v = make_float4(0.f, 0.f, 0.f, 0.f);
            if (node < N_NODES) v = x4[(size_t)node * 32 + c4];
            __half2 h01 = __halves2half2(__float2half(v.x), __float2half(v.y));
            __half2 h23 = __halves2half2(__float2half(v.z), __float2half(v.w));
            float2 pk;
            pk.x = *(float*)&h01;
            pk.y = *(float*)&h23;
            *(float2*)&sXh[r * XH + c4 * 4] = pk;
        }
        __syncthreads();
        int rp = t >> 3, cp = t & 7;                 // 32 row-pairs x 8 col-pairs
        const __half* xr0 = &sXh[(2 * rp)     * XH];
        const __half* xr1 = &sXh[(2 * rp + 1) * XH];
        const float*  wr0 = &sWt[(2 * cp)     * XPADW];
        const float*  wr1 = &sWt[(2 * cp + 1) * XPADW];
        float4 A00 = make_float4(0.f, 0.f, 0.f, 0.f);
        float4 A01 = A00, A10 = A00, A11 = A00;
        #pragma unroll 4
        for (int kk = 0; kk < 16; ++kk) {            // 8 k's per iteration
            float4 hx0 = *(const float4*)&xr0[kk * 8];
            float4 hx1 = *(const float4*)&xr1[kk * 8];
            float4 w0a = *(const float4*)&wr0[kk * 8];
            float4 w0b = *(const float4*)&wr0[kk * 8 + 4];
            float4 w1a = *(const float4*)&wr1[kk * 8];
            float4 w1b = *(const float4*)&wr1[kk * 8 + 4];
            float2 x00 = unpk_half2(hx0.x), x01 = unpk_half2(hx0.y);
            float2 x02 = unpk_half2(hx0.z), x03 = unpk_half2(hx0.w);
            float2 x10 = unpk_half2(hx1.x), x11 = unpk_half2(hx1.y);
            float2 x12 = unpk_half2(hx1.z), x13 = unpk_half2(hx1.w);
            A00.x += x00.x * w0a.x; A00.y += x00.y * w0a.y;
            A00.z += x01.x * w0a.z; A00.w += x01.y * w0a.w;
            A00.x += x02.x * w0b.x; A00.y += x02.y * w0b.y;
            A00.z += x03.x * w0b.z; A00.w += x03.y * w0b.w;
            A01.x += x00.x * w1a.x; A01.y += x00.y * w1a.y;
            A01.z += x01.x * w1a.z; A01.w += x01.y * w1a.w;
            A01.x += x02.x * w1b.x; A01.y += x02.y * w1b.y;
            A01.z += x03.x * w1b.z; A01.w += x03.y * w1b.w;
            A10.x += x10.x * w0a.x; A10.y += x10.y * w0a.y;
            A10.z += x11.x * w0a.z; A10.w += x11.y * w0a.w;
            A10.x += x12.x * w0b.x; A10.y += x12.y * w0b.y;
            A10.z += x13.x * w0b.z; A10.w += x13.y * w0b.w;
            A11.x += x10.x * w1a.x; A11.y += x10.y * w1a.y;
            A11.z += x11.x * w1a.z; A11.w += x11.y * w1a.w;
            A11.x += x12.x * w1b.x; A11.y += x12.y * w1b.y;
            A11.z += x13.x * w1b.z; A11.w += x13.y * w1b.w;
        }
        float h00 = A00.x + A00.y + A00.z + A00.w;   // node 2rp,   col 2cp
        float h01 = A01.x + A01.y + A01.z + A01.w;   // node 2rp,   col 2cp+1
        float h10 = A10.x + A10.y + A10.z + A10.w;   // node 2rp+1, col 2cp
        float h11 = A11.x + A11.y + A11.z + A11.w;   // node 2rp+1, col 2cp+1
        float ad0 = att_d[2 * cp], ad1 = att_d[2 * cp + 1];
        float pd0 = h00 * ad0 + h01 * ad1;
        float pd1 = h10 * ad0 + h11 * ad1;
        #pragma unroll
        for (int off = 1; off < 8; off <<= 1) {
            pd0 += __shfl_xor(pd0, off);
            pd1 += __shfl_xor(pd1, off);
        }
        int n0 = node0 + 2 * rp, n1 = n0 + 1;
        __half2* hp = (__half2*)h1f;
        if (n0 < N_NODES) {
            hp[(size_t)n0 * 8 + cp] = __halves2half2(__float2half(h00), __float2half(h01));
            if (cp == 0) a_dst[n0] = pd0;
        }
        if (n1 < N_NODES) {
            hp[(size_t)n1 * 8 + cp] = __halves2half2(__float2half(h10), __float2half(h11));
            if (cp == 0) a_dst[n1] = pd1;
        }
    }
}

// ======== half-bucket binning: filter parent's pairs by half, hist(64)+scan+scatter ====
__device__ __forceinline__ void bin_half(int parent, int half,
        const unsigned* __restrict__ pairs, const int* __restrict__ gcnt,
        int* lcsr, int* ccnt, int* sexc, int* cur) {
    int t = threadIdx.x;
    if (t < 64) ccnt[t] = 0;
    __syncthreads();
    int tot = gcnt[parent];
    if (tot > CAP) tot = CAP; if (tot < 0) tot = 0;
    size_t pb = (size_t)parent * CAP;
    for (int i = t; i < tot; i += 256) {
        unsigned v = pairs[pb + i];
        int dl = (int)(v & 127u);
        if ((dl >> 6) == half) atomicAdd(&ccnt[dl & 63], 1);
    }
    __syncthreads();
    if (t < 64) sexc[t] = ccnt[t];
    __syncthreads();
    for (int off = 1; off < 64; off <<= 1) {
        int xv = 0;
        if (t < 64 && t >= off) xv = sexc[t - off];
        __syncthreads();
        if (t < 64) sexc[t] += xv;
        __syncthreads();
    }
    if (t < 64) cur[t] = sexc[t] - ccnt[t];
    __syncthreads();
    for (int i = t; i < tot; i += 256) {
        unsigned v = pairs[pb + i];
        int dl = (int)(v & 127u);
        if ((dl >> 6) == half) {
            int pos = atomicAdd(&cur[dl & 63], 1);
            if (pos < HCAP) lcsr[pos] = (int)(v >> 7);
        }
    }
    __syncthreads();
}

// ===== layer-1: half-bucket bin + r5 gather engine (pair-split, butterfly) + epilogue
__global__ __launch_bounds__(256) void bgat1_k(
    const unsigned* __restrict__ pairs, const int* __restrict__ gcnt,
    const __half* __restrict__ h1f, const float* __restrict__ att_s1,
    const float* __restrict__ adst1, const float* __restrict__ b1,
    const float* __restrict__ W2, const float* __restrict__ as2,
    const float* __restrict__ ad2, float4* __restrict__ h2p,
    float* __restrict__ adst2) {
    __shared__ __align__(16) int lcsr[HCAP];       // 11264 B
    __shared__ int ccnt[64], sexc[64], cur[64];    //   768 B
    __shared__ __align__(16) float sW2t[OUTC][20]; //   400 B
    __shared__ __align__(16) float sG[16][16];     //  1024 B
    __shared__ __align__(16) float sH2[16][8];     //   512 B
    __shared__ __align__(16) float sAsd[16];       //    64 B
    int t = threadIdx.x;
    int parent = blockIdx.x >> 1, half = blockIdx.x & 1;
    if (t < 16) sAsd[t] = 0.0f;
    if (t < HID * OUTC) sW2t[t % OUTC][t / OUTC] = W2[t];
    if (t < OUTC) { sAsd[t] = as2[t]; sAsd[8 + t] = ad2[t]; }
    int lane = t & 15;
    int sub  = lane & 1;        // half-row owner
    int eslot = lane >> 1;      // 8 edge slots
    int ch = sub * 8 + ((lane >> 1) & 1) * 4 + ((lane >> 2) & 1) * 2 + ((lane >> 3) & 1);
    float rB1 = b1[ch];
    float attr[8];
    #pragma unroll
    for (int j = 0; j < 8; ++j) attr[j] = att_s1[sub * 8 + j];

    bin_half(parent, half, pairs, gcnt, lcsr, ccnt, sexc, cur);

    int nl = t >> 4;            // 0..15: node group within pass
    for (int pass = 0; pass < 4; ++pass) {
        int nloc = pass * 16 + nl;           // 0..63
        int node = (parent << 7) + (half << 6) + nloc;
        int cc = ccnt[nloc];
        int excl = sexc[nloc] - cc;
        int len = cc;
        if (excl + len > HCAP) len = (excl < HCAP) ? (HCAP - excl) : 0;
        int start = excl;
        float ad = (node < N_NODES) ? adst1[node] : 0.0f;

        float acc[8];
        #pragma unroll
        for (int c = 0; c < 8; ++c) acc[c] = 0.0f;
        float accd = 0.0f;
        int it = eslot;
        for (; it + 8 < len; it += 16) {
            int s0 = lcsr[start + it];
            int s1 = lcsr[start + it + 8];
            float4 p = *(const float4*)(h1f + (size_t)s0 * HID + sub * 8);
            float4 q = *(const float4*)(h1f + (size_t)s1 * HID + sub * 8);
            float2 f0 = unpk_half2(p.x), f1 = unpk_half2(p.y);
            float2 f2 = unpk_half2(p.z), f3 = unpk_half2(p.w);
            float2 g0 = unpk_half2(q.x), g1 = unpk_half2(q.y);
            float2 g2 = unpk_half2(q.z), g3 = unpk_half2(q.w);
            float pp0 = f0.x*attr[0] + f0.y*attr[1] + f1.x*attr[2] + f1.y*attr[3]
                      + f2.x*attr[4] + f2.y*attr[5] + f3.x*attr[6] + f3.y*attr[7];
            float pp1 = g0.x*attr[0] + g0.y*attr[1] + g1.x*attr[2] + g1.y*attr[3]
                      + g2.x*attr[4] + g2.y*attr[5] + g3.x*attr[6] + g3.y*attr[7];
            float v0 = pp0 + __shfl_xor(pp0, 1) + ad;
            float v1 = pp1 + __shfl_xor(pp1, 1) + ad;
            v0 = (v0 > 0.0f) ? v0 : NEG_SLOPE * v0;
            v1 = (v1 > 0.0f) ? v1 : NEG_SLOPE * v1;
            float e0 = __expf(v0), e1 = __expf(v1);
            accd += e0 + e1;
            acc[0] += e0 * f0.x + e1 * g0.x; acc[1] += e0 * f0.y + e1 * g0.y;
            acc[2] += e0 * f1.x + e1 * g1.x; acc[3] += e0 * f1.y + e1 * g1.y;
            acc[4] += e0 * f2.x + e1 * g2.x; acc[5] += e0 * f2.y + e1 * g2.y;
            acc[6] += e0 * f3.x + e1 * g3.x; acc[7] += e0 * f3.y + e1 * g3.y;
        }
        if (it < len) {
            int s = lcsr[start + it];
            float4 p = *(const float4*)(h1f + (size_t)s * HID + sub * 8);
            float2 f0 = unpk_half2(p.x), f1 = unpk_half2(p.y);
            float2 f2 = unpk_half2(p.z), f3 = unpk_half2(p.w);
            float pp = f0.x*attr[0] + f0.y*attr[1] + f1.x*attr[2] + f1.y*attr[3]
                     + f2.x*attr[4] + f2.y*attr[5] + f3.x*attr[6] + f3.y*attr[7];
            float v = pp + __shfl_xor(pp, 1) + ad;
            v = (v > 0.0f) ? v : NEG_SLOPE * v;
            float ex = __expf(v);
            accd += ex;
            acc[0] += ex * f0.x; acc[1] += ex * f0.y;
            acc[2] += ex * f1.x; acc[3] += ex * f1.y;
            acc[4] += ex * f2.x; acc[5] += ex * f2.y;
            acc[6] += ex * f3.x; acc[7] += ex * f3.y;
        }
        // halving butterfly across 8 edge-slots (xor 2,4,8): 7 shuffles
        {
            bool b2 = (lane & 2) != 0;
            #pragma unroll
            for (int c = 0; c < 4; ++c) {
                float send = b2 ? acc[c] : acc[c + 4];
                float r = __shfl_xor(send, 2);
                acc[c] = (b2 ? acc[c + 4] : acc[c]) + r;
            }
            bool b4 = (lane & 4) != 0;
            #pragma unroll
            for (int c = 0; c < 2; ++c) {
                float send = b4 ? acc[c] : acc[c + 2];
                float r = __shfl_xor(send, 4);
                acc[c] = (b4 ? acc[c + 2] : acc[c]) + r;
            }
            bool b8 = (lane & 8) != 0;
            {
                float send = b8 ? acc[0] : acc[1];
                float r = __shfl_xor(send, 8);
                acc[0] = (b8 ? acc[1] : acc[0]) + r;
            }
        }
        accd += __shfl_xor(accd, 2);
        accd += __shfl_xor(accd, 4);
        accd += __shfl_xor(accd, 8);

        float inv = 1.0f / (accd + 1e-16f);
        float g = fmaxf(acc[0] * inv + rB1, 0.0f);   // lane holds channel ch
        sG[nl][ch] = g;              // wave-local write/read: no sync needed
        if (lane < OUTC) {
            const float4* gp = (const float4*)sG[nl];
            const float4* wp = (const float4*)sW2t[lane];
            float h2v = 0.0f;
            #pragma unroll
            for (int k4 = 0; k4 < 4; ++k4) {
                float4 gv = gp[k4], wv = wp[k4];
                h2v += gv.x * wv.x + gv.y * wv.y + gv.z * wv.z + gv.w * wv.w;
            }
            sH2[nl][lane] = h2v;
            if (lane == 0 && node < N_NODES) {
                float4 hv = *(const float4*)&sH2[nl][0];
                float h24 = sH2[nl][4];
                float4 as4 = *(const float4*)&sAsd[0]; float as_4 = sAsd[4];
                float4 ad4 = *(const float4*)&sAsd[8]; float ad_4 = sAsd[12];
                float s2 = hv.x * as4.x + hv.y * as4.y + hv.z * as4.z + hv.w * as4.w + h24 * as_4;
                float d2 = hv.x * ad4.x + hv.y * ad4.y + hv.z * ad4.z + hv.w * ad4.w + h24 * ad_4;
                adst2[node] = d2;
                float4 r;
                r.x = s2;
                r.y = pk_half2(hv.x, hv.y);
                r.z = pk_half2(hv.z, hv.w);
                r.w = pk_half2(h24, 0.0f);
                h2p[node] = r;
            }
        }
    }
}

// ===== layer-2: half-bucket bin + r5 gat2 engine + log_softmax =====
__global__ __launch_bounds__(256) void bgat2_k(
    const unsigned* __restrict__ pairs, const int* __restrict__ gcnt,
    const float4* __restrict__ h2p, const float* __restrict__ adst2,
    const float* __restrict__ b2, float* __restrict__ out) {
    __shared__ __align__(16) int lcsr[HCAP];
    __shared__ int ccnt[64], sexc[64], cur[64];
    __shared__ float sB2[8];
    int t = threadIdx.x;
    int parent = blockIdx.x >> 1, half = blockIdx.x & 1;
    if (t < OUTC) sB2[t] = b2[t];

    bin_half(parent, half, pairs, gcnt, lcsr, ccnt, sexc, cur);

    int lane = t & 15;
    int nl = t >> 4;
    for (int pass = 0; pass < 4; ++pass) {
        int nloc = pass * 16 + nl;
        int node = (parent << 7) + (half << 6) + nloc;
        int cc = ccnt[nloc];
        int excl = sexc[nloc] - cc;
        int len = cc;
        if (excl + len > HCAP) len = (excl < HCAP) ? (HCAP - excl) : 0;
        int start = excl;
        float ad = (node < N_NODES) ? adst2[node] : 0.0f;

        float acc[OUTC];
        #pragma unroll
        for (int c = 0; c < OUTC; ++c) acc[c] = 0.0f;
        float accd = 0.0f;
        int it = lane;
        for (; it + 16 < len; it += 32) {
            int s0 = lcsr[start + it];
            int s1 = lcsr[start + it + 16];
            float4 r0 = h2p[s0];
            float4 r1 = h2p[s1];
            float v0 = r0.x + ad;
            float v1 = r1.x + ad;
            v0 = (v0 > 0.0f) ? v0 : NEG_SLOPE * v0;
            v1 = (v1 > 0.0f) ? v1 : NEG_SLOPE * v1;
            float e0 = __expf(v0), e1 = __expf(v1);
            accd += e0 + e1;
            float2 a01 = unpk_half2(r0.y), a23 = unpk_half2(r0.z), a4 = unpk_half2(r0.w);
            float2 b01 = unpk_half2(r1.y), b23 = unpk_half2(r1.z), b4 = unpk_half2(r1.w);
            acc[0] += e0 * a01.x + e1 * b01.x;
            acc[1] += e0 * a01.y + e1 * b01.y;
            acc[2] += e0 * a23.x + e1 * b23.x;
            acc[3] += e0 * a23.y + e1 * b23.y;
            acc[4] += e0 * a4.x  + e1 * b4.x;
        }
        if (it < len) {
            int s = lcsr[start + it];
            float4 r = h2p[s];
            float v = r.x + ad;
            v = (v > 0.0f) ? v : NEG_SLOPE * v;
            float ex = __expf(v);
            accd += ex;
            float2 f01 = unpk_half2(r.y), f23 = unpk_half2(r.z), f4 = unpk_half2(r.w);
            acc[0] += ex * f01.x; acc[1] += ex * f01.y;
            acc[2] += ex * f23.x; acc[3] += ex * f23.y;
            acc[4] += ex * f4.x;
        }
        #pragma unroll
        for (int off = 8; off; off >>= 1) {
            accd += __shfl_xor(accd, off);
            #pragma unroll
            for (int c = 0; c < OUTC; ++c) acc[c] += __shfl_xor(acc[c], off);
        }
        if (lane == 0 && node < N_NODES) {
            float inv = 1.0f / (accd + 1e-16f);
            float val[OUTC];
            float mx = -3.4e38f;
            #pragma unroll
            for (int c = 0; c < OUTC; ++c) {
                val[c] = acc[c] * inv + sB2[c];
                mx = fmaxf(mx, val[c]);
            }
            float se = 0.0f;
            #pragma unroll
            for (int c = 0; c < OUTC; ++c) se += __expf(val[c] - mx);
            float lse = logf(se) + mx;
            #pragma unroll
            for (int c = 0; c < OUTC; ++c)
                out[(size_t)node * OUTC + c] = val[c] - lse;
        }
    }
}

extern "C" void kernel_launch(void* const* d_in, const int* in_sizes, int n_in,
                              void* d_out, int out_size, void* d_ws, size_t ws_size,
                              hipStream_t stream) {
    const float* x   = (const float*)d_in[0];
    const int*   ei  = (const int*)d_in[1];
    const float* W1  = (const float*)d_in[2];
    const float* as1 = (const float*)d_in[3];
    const float* ad1 = (const float*)d_in[4];
    const float* b1  = (const float*)d_in[5];
    const float* W2  = (const float*)d_in[6];
    const float* as2 = (const float*)d_in[7];
    const float* ad2 = (const float*)d_in[8];
    const float* b2  = (const float*)d_in[9];
    float* out = (float*)d_out;

    // workspace layout (bytes), ~21.6 MB (r9/r10-verified footprint):
    //  pairs  @0           782*5120*4 = 16,015,360
    //  h1f    @16,015,360  3,200,000
    //  adst1  @19,215,360  400,000
    //  h2p    @19,615,360  1,600,000
    //  adst2  @21,215,360  400,000
    //  gcnt   @21,615,360  3,128
    char* wsb = (char*)d_ws;
    unsigned* pairs = (unsigned*)wsb;
    __half* h1f     = (__half*)(wsb + 16015360);
    float*  adst1   = (float*)(wsb + 19215360);
    float4* h2p     = (float4*)(wsb + 19615360);
    float*  adst2   = (float*)(wsb + 21215360);
    int*    gcnt    = (int*)(wsb + 21615360);

    // ---- zero bucket totals ----
    hipMemsetAsync(gcnt, 0, NBKT * sizeof(int), stream);
    // ---- fused: edge partition (403 blocks) + layer-1 projection (1563 tiles) ----
    partproj_k<<<PART_TILES + PROJ_TILES, 256, 0, stream>>>(
        ei, gcnt, pairs, x, W1, ad1, h1f, adst1);
    // ---- layer-1: half-bucket bin + aggregate + relu + proj2 (1564 blocks) ----
    bgat1_k<<<NBKT * 2, 256, 0, stream>>>(pairs, gcnt, h1f, as1, adst1, b1,
                                          W2, as2, ad2, h2p, adst2);
    // ---- layer-2: half-bucket bin + aggregate + log_softmax (1564 blocks) ----
    bgat2_k<<<NBKT * 2, 256, 0, stream>>>(pairs, gcnt, h2p, adst2, b2, out);
}

// Round 13
// 218.886 us; speedup vs baseline: 1.0862x; 1.0862x over previous
//
#include <hip/hip_runtime.h>
#include <hip/hip_fp16.h>

#define N_NODES 100000
#define N_EDGES 3200000
#define E_TOT   (N_EDGES + N_NODES)   // 3.3M edges incl self-loops
#define IN_C 128
#define HID  16
#define OUTC 5
#define NEG_SLOPE 0.2f

#define NBKT 782        // buckets of 128 dsts: b = dst >> 7
#define CAP  5120       // per-bucket pairs capacity (mean 4220, +~13 sigma)
#define P_TILE 4096
#define PART_TILES ((E_TOT + P_TILE - 1) / P_TILE)  // 806
#define NT 64                                        // nodes per projection tile
#define PROJ_TILES ((N_NODES + NT - 1) / NT)         // 1563
#define AGG_GRID ((N_NODES + 15) / 16)               // 6250 (gat2 grid)
#define XH 136          // sXh row stride in halves (272B rows, 2-way alias = free)
#define XPADW 132       // sWt row stride in floats

__device__ __forceinline__ float pk_half2(float a, float b) {
    __half2 h = __halves2half2(__float2half(a), __float2half(b));
    return *(float*)&h;
}
__device__ __forceinline__ float2 unpk_half2(float v) {
    return __half22float2(*(__half2*)&v);
}

// ============ fused: edge partition (blocks 0..805) + layer-1 projection ============
// (r10-verified form: 782 buckets, staged vbuf/bbuf, P_TILE 4096, fp16 proj tile)
__global__ __launch_bounds__(256) void partproj_k(
    const int* __restrict__ ei, int* __restrict__ gcnt, unsigned* __restrict__ pairs,
    const float* __restrict__ x, const float* __restrict__ W1,
    const float* __restrict__ att_d,
    __half* __restrict__ h1f, float* __restrict__ a_dst) {
    __shared__ __align__(16) char smem[30848];
    int t = threadIdx.x;
    if (blockIdx.x < PART_TILES) {
        unsigned* vbuf       = (unsigned*)smem;                  // 16384 B
        unsigned short* bbuf = (unsigned short*)(smem + 16384);  //  8192 B
        int* hist            = (int*)(smem + 24576);             //  3128 B
        int* cur             = (int*)(smem + 27704);             //  3128 B
        for (int i = t; i < NBKT; i += 256) hist[i] = 0;
        __syncthreads();
        int base = blockIdx.x * P_TILE;
        int lim = E_TOT - base; if (lim > P_TILE) lim = P_TILE;
        for (int i = t; i < lim; i += 256) {
            int e = base + i;
            int s, d;
            if (e < N_EDGES) { s = ei[e]; d = ei[N_EDGES + e]; }
            else             { s = e - N_EDGES; d = s; }
            int b = d >> 7;
            vbuf[i] = ((unsigned)s << 7) | (unsigned)(d & 127);
            bbuf[i] = (unsigned short)b;
            atomicAdd(&hist[b], 1);
        }
        __syncthreads();
        for (int i = t; i < NBKT; i += 256) {
            int h = hist[i];
            cur[i] = h ? atomicAdd(&gcnt[i], h) : 0;   // reserve [cur, cur+h)
        }
        __syncthreads();
        for (int i = t; i < lim; i += 256) {
            int b = bbuf[i];
            int p = atomicAdd(&cur[b], 1);
            if (p >= 0 && p < CAP) pairs[(size_t)b * CAP + p] = vbuf[i];
        }
    } else {
        __half* sXh = (__half*)smem;           // 64 x 136 halves = 17408 B
        float*  sWt = (float*)(smem + 17408);  // 16 x 132 floats =  8448 B
        int bid = blockIdx.x - PART_TILES;
        int node0 = bid * NT;
        for (int i = t; i < IN_C * HID; i += 256) {
            int k = i >> 4, c = i & 15;
            sWt[c * XPADW + k] = W1[i];
        }
        const float4* x4 = (const float4*)x;
        for (int i = t; i < NT * 32; i += 256) {     // 2048 float4
            int r = i >> 5, c4 = i & 31;
            int node = node0 + r;
            float4 v = make_float4(0.f, 0.f, 0.f, 0.f);
            if (node < N_NODES) v = x4[(size_t)node * 32 + c4];
            __half2 h01 = __halves2half2(__float2half(v.x), __float2half(v.y));
            __half2 h23 = __halves2half2(__float2half(v.z), __float2half(v.w));
            float2 pk;
            pk.x = *(float*)&h01;
            pk.y = *(float*)&h23;
            *(float2*)&sXh[r * XH + c4 * 4] = pk;
        }
        __syncthreads();
        int rp = t >> 3, cp = t & 7;                 // 32 row-pairs x 8 col-pairs
        const __half* xr0 = &sXh[(2 * rp)     * XH];
        const __half* xr1 = &sXh[(2 * rp + 1) * XH];
        const float*  wr0 = &sWt[(2 * cp)     * XPADW];
        const float*  wr1 = &sWt[(2 * cp + 1) * XPADW];
        float4 A00 = make_float4(0.f, 0.f, 0.f, 0.f);
        float4 A01 = A00, A10 = A00, A11 = A00;
        #pragma unroll 4
        for (int kk = 0; kk < 16; ++kk) {            // 8 k's per iteration
            float4 hx0 = *(const float4*)&xr0[kk * 8];
            float4 hx1 = *(const float4*)&xr1[kk * 8];
            float4 w0a = *(const float4*)&wr0[kk * 8];
            float4 w0b = *(const float4*)&wr0[kk * 8 + 4];
            float4 w1a = *(const float4*)&wr1[kk * 8];
            float4 w1b = *(const float4*)&wr1[kk * 8 + 4];
            float2 x00 = unpk_half2(hx0.x), x01 = unpk_half2(hx0.y);
            float2 x02 = unpk_half2(hx0.z), x03 = unpk_half2(hx0.w);
            float2 x10 = unpk_half2(hx1.x), x11 = unpk_half2(hx1.y);
            float2 x12 = unpk_half2(hx1.z), x13 = unpk_half2(hx1.w);
            A00.x += x00.x * w0a.x; A00.y += x00.y * w0a.y;
            A00.z += x01.x * w0a.z; A00.w += x01.y * w0a.w;
            A00.x += x02.x * w0b.x; A00.y += x02.y * w0b.y;
            A00.z += x03.x * w0b.z; A00.w += x03.y * w0b.w;
            A01.x += x00.x * w1a.x; A01.y += x00.y * w1a.y;
            A01.z += x01.x * w1a.z; A01.w += x01.y * w1a.w;
            A01.x += x02.x * w1b.x; A01.y += x02.y * w1b.y;
            A01.z += x03.x * w1b.z; A01.w += x03.y * w1b.w;
            A10.x += x10.x * w0a.x; A10.y += x10.y * w0a.y;
            A10.z += x11.x * w0a.z; A10.w += x11.y * w0a.w;
            A10.x += x12.x * w0b.x; A10.y += x12.y * w0b.y;
            A10.z += x13.x * w0b.z; A10.w += x13.y * w0b.w;
            A11.x += x10.x * w1a.x; A11.y += x10.y * w1a.y;
            A11.z += x11.x * w1a.z; A11.w += x11.y * w1a.w;
            A11.x += x12.x * w1b.x; A11.y += x12.y * w1b.y;
            A11.z += x13.x * w1b.z; A11.w += x13.y * w1b.w;
        }
        float h00 = A00.x + A00.y + A00.z + A00.w;   // node 2rp,   col 2cp
        float h01 = A01.x + A01.y + A01.z + A01.w;   // node 2rp,   col 2cp+1
        float h10 = A10.x + A10.y + A10.z + A10.w;   // node 2rp+1, col 2cp
        float h11 = A11.x + A11.y + A11.z + A11.w;   // node 2rp+1, col 2cp+1
        float ad0 = att_d[2 * cp], ad1 = att_d[2 * cp + 1];
        float pd0 = h00 * ad0 + h01 * ad1;
        float pd1 = h10 * ad0 + h11 * ad1;
        #pragma unroll
        for (int off = 1; off < 8; off <<= 1) {
            pd0 += __shfl_xor(pd0, off);
            pd1 += __shfl_xor(pd1, off);
        }
        int n0 = node0 + 2 * rp, n1 = n0 + 1;
        __half2* hp = (__half2*)h1f;
        if (n0 < N_NODES) {
            hp[(size_t)n0 * 8 + cp] = __halves2half2(__float2half(h00), __float2half(h01));
            if (cp == 0) a_dst[n0] = pd0;
        }
        if (n1 < N_NODES) {
            hp[(size_t)n1 * 8 + cp] = __halves2half2(__float2half(h10), __float2half(h11));
            if (cp == 0) a_dst[n1] = pd1;
        }
    }
}

// ======== bucket binning: hist(128) + scan + scatter pairs into LDS lcsr ========
// Positions provably in [0, tot): scan total == stored count, so no bounds checks.
__device__ __forceinline__ int bin_bucket(int b, const unsigned* __restrict__ pairs,
        const int* __restrict__ gcnt, int* lcsr, int* ccnt, int* sexc, int* cur) {
    int t = threadIdx.x;
    if (t < 128) ccnt[t] = 0;
    __syncthreads();
    int tot = gcnt[b];
    if (tot > CAP) tot = CAP; if (tot < 0) tot = 0;
    size_t pb = (size_t)b * CAP;
    for (int i = t; i < tot; i += 512)
        atomicAdd(&ccnt[pairs[pb + i] & 127u], 1);
    __syncthreads();
    if (t < 128) sexc[t] = ccnt[t];
    __syncthreads();
    for (int off = 1; off < 128; off <<= 1) {
        int xv = 0;
        if (t < 128 && t >= off) xv = sexc[t - off];
        __syncthreads();
        if (t < 128) sexc[t] += xv;
        __syncthreads();
    }
    if (t < 128) cur[t] = sexc[t] - ccnt[t];
    __syncthreads();
    for (int i = t; i < tot; i += 512) {
        unsigned v = pairs[pb + i];
        int pos = atomicAdd(&cur[v & 127u], 1);
        lcsr[pos] = (int)(v >> 7);
    }
    __syncthreads();
    return tot;
}

// ===== layer-1: bin + gather engine + epilogue; EXPORTS bins (in-place csr + rs_cnt)
// so layer 2 needs no binning at all.
__global__ __launch_bounds__(512) void bgat1_k(
    unsigned* __restrict__ pairs, const int* __restrict__ gcnt,
    const __half* __restrict__ h1f, const float* __restrict__ att_s1,
    const float* __restrict__ adst1, const float* __restrict__ b1,
    const float* __restrict__ W2, const float* __restrict__ as2,
    const float* __restrict__ ad2, float4* __restrict__ h2p,
    float* __restrict__ adst2, int2* __restrict__ rs_cnt) {
    __shared__ __align__(16) int lcsr[CAP];        // 20480 B
    __shared__ int ccnt[128], sexc[128], cur[128]; //  1536 B
    __shared__ __align__(16) float sW2t[OUTC][20]; //   400 B
    __shared__ __align__(16) float sG[32][16];     //  2048 B
    __shared__ __align__(16) float sH2[32][8];     //  1024 B
    __shared__ __align__(16) float sAsd[16];       //    64 B
    int t = threadIdx.x;
    int b = blockIdx.x;
    if (t < 16) sAsd[t] = 0.0f;
    if (t < HID * OUTC) sW2t[t % OUTC][t / OUTC] = W2[t];
    if (t < OUTC) { sAsd[t] = as2[t]; sAsd[8 + t] = ad2[t]; }
    int lane = t & 15;
    int sub  = lane & 1;        // half-row owner
    int eslot = lane >> 1;      // 8 edge slots
    int ch = sub * 8 + ((lane >> 1) & 1) * 4 + ((lane >> 2) & 1) * 2 + ((lane >> 3) & 1);
    float rB1 = b1[ch];
    float attr[8];
    #pragma unroll
    for (int j = 0; j < 8; ++j) attr[j] = att_s1[sub * 8 + j];

    int tot = bin_bucket(b, pairs, gcnt, lcsr, ccnt, sexc, cur);

    // ---- export bins: in-place sorted csr over this bucket's (now-dead) pairs
    //      region (linear coalesced store) + per-node (start,len) ----
    size_t pb = (size_t)b * CAP;
    for (int i = t; i < tot; i += 512) pairs[pb + i] = (unsigned)lcsr[i];
    if (t < 128) {
        int node = (b << 7) + t;
        if (node < N_NODES)
            rs_cnt[node] = make_int2((int)pb + (sexc[t] - ccnt[t]), ccnt[t]);
    }

    int nl = t >> 4;            // 0..31: node group within pass
    for (int pass = 0; pass < 4; ++pass) {
        int nloc = pass * 32 + nl;           // 0..127
        int node = (b << 7) + nloc;
        int len = ccnt[nloc];
        int start = sexc[nloc] - len;
        float ad = (node < N_NODES) ? adst1[node] : 0.0f;

        float acc[8];
        #pragma unroll
        for (int c = 0; c < 8; ++c) acc[c] = 0.0f;
        float accd = 0.0f;
        int it = eslot;
        for (; it + 8 < len; it += 16) {
            int s0 = lcsr[start + it];
            int s1 = lcsr[start + it + 8];
            float4 p = *(const float4*)(h1f + (size_t)s0 * HID + sub * 8);
            float4 q = *(const float4*)(h1f + (size_t)s1 * HID + sub * 8);
            float2 f0 = unpk_half2(p.x), f1 = unpk_half2(p.y);
            float2 f2 = unpk_half2(p.z), f3 = unpk_half2(p.w);
            float2 g0 = unpk_half2(q.x), g1 = unpk_half2(q.y);
            float2 g2 = unpk_half2(q.z), g3 = unpk_half2(q.w);
            float pp0 = f0.x*attr[0] + f0.y*attr[1] + f1.x*attr[2] + f1.y*attr[3]
                      + f2.x*attr[4] + f2.y*attr[5] + f3.x*attr[6] + f3.y*attr[7];
            float pp1 = g0.x*attr[0] + g0.y*attr[1] + g1.x*attr[2] + g1.y*attr[3]
                      + g2.x*attr[4] + g2.y*attr[5] + g3.x*attr[6] + g3.y*attr[7];
            float v0 = pp0 + __shfl_xor(pp0, 1) + ad;
            float v1 = pp1 + __shfl_xor(pp1, 1) + ad;
            v0 = (v0 > 0.0f) ? v0 : NEG_SLOPE * v0;
            v1 = (v1 > 0.0f) ? v1 : NEG_SLOPE * v1;
            float e0 = __expf(v0), e1 = __expf(v1);
            accd += e0 + e1;
            acc[0] += e0 * f0.x + e1 * g0.x; acc[1] += e0 * f0.y + e1 * g0.y;
            acc[2] += e0 * f1.x + e1 * g1.x; acc[3] += e0 * f1.y + e1 * g1.y;
            acc[4] += e0 * f2.x + e1 * g2.x; acc[5] += e0 * f2.y + e1 * g2.y;
            acc[6] += e0 * f3.x + e1 * g3.x; acc[7] += e0 * f3.y + e1 * g3.y;
        }
        if (it < len) {
            int s = lcsr[start + it];
            float4 p = *(const float4*)(h1f + (size_t)s * HID + sub * 8);
            float2 f0 = unpk_half2(p.x), f1 = unpk_half2(p.y);
            float2 f2 = unpk_half2(p.z), f3 = unpk_half2(p.w);
            float pp = f0.x*attr[0] + f0.y*attr[1] + f1.x*attr[2] + f1.y*attr[3]
                     + f2.x*attr[4] + f2.y*attr[5] + f3.x*attr[6] + f3.y*attr[7];
            float v = pp + __shfl_xor(pp, 1) + ad;
            v = (v > 0.0f) ? v : NEG_SLOPE * v;
            float ex = __expf(v);
            accd += ex;
            acc[0] += ex * f0.x; acc[1] += ex * f0.y;
            acc[2] += ex * f1.x; acc[3] += ex * f1.y;
            acc[4] += ex * f2.x; acc[5] += ex * f2.y;
            acc[6] += ex * f3.x; acc[7] += ex * f3.y;
        }
        // halving butterfly across 8 edge-slots (xor 2,4,8): 7 shuffles
        {
            bool b2 = (lane & 2) != 0;
            #pragma unroll
            for (int c = 0; c < 4; ++c) {
                float send = b2 ? acc[c] : acc[c + 4];
                float r = __shfl_xor(send, 2);
                acc[c] = (b2 ? acc[c + 4] : acc[c]) + r;
            }
            bool b4 = (lane & 4) != 0;
            #pragma unroll
            for (int c = 0; c < 2; ++c) {
                float send = b4 ? acc[c] : acc[c + 2];
                float r = __shfl_xor(send, 4);
                acc[c] = (b4 ? acc[c + 2] : acc[c]) + r;
            }
            bool b8 = (lane & 8) != 0;
            {
                float send = b8 ? acc[0] : acc[1];
                float r = __shfl_xor(send, 8);
                acc[0] = (b8 ? acc[1] : acc[0]) + r;
            }
        }
        accd += __shfl_xor(accd, 2);
        accd += __shfl_xor(accd, 4);
        accd += __shfl_xor(accd, 8);

        float inv = 1.0f / (accd + 1e-16f);
        float g = fmaxf(acc[0] * inv + rB1, 0.0f);   // lane holds channel ch
        sG[nl][ch] = g;              // wave-local write/read: no sync needed
        if (lane < OUTC) {
            const float4* gp = (const float4*)sG[nl];
            const float4* wp = (const float4*)sW2t[lane];
            float h2v = 0.0f;
            #pragma unroll
            for (int k4 = 0; k4 < 4; ++k4) {
                float4 gv = gp[k4], wv = wp[k4];
                h2v += gv.x * wv.x + gv.y * wv.y + gv.z * wv.z + gv.w * wv.w;
            }
            sH2[nl][lane] = h2v;
            if (lane == 0 && node < N_NODES) {
                float4 hv = *(const float4*)&sH2[nl][0];
                float h24 = sH2[nl][4];
                float4 as4 = *(const float4*)&sAsd[0]; float as_4 = sAsd[4];
                float4 ad4 = *(const float4*)&sAsd[8]; float ad_4 = sAsd[12];
                float s2 = hv.x * as4.x + hv.y * as4.y + hv.z * as4.z + hv.w * as4.w + h24 * as_4;
                float d2 = hv.x * ad4.x + hv.y * ad4.y + hv.z * ad4.z + hv.w * ad4.w + h24 * ad_4;
                adst2[node] = d2;
                float4 r;
                r.x = s2;
                r.y = pk_half2(hv.x, hv.y);
                r.z = pk_half2(hv.z, hv.w);
                r.w = pk_half2(h24, 0.0f);
                h2p[node] = r;
            }
        }
    }
}

// ===== layer-2 aggregate (r5-verified engine): 16 lanes/node, unroll-2, full
// occupancy (no big LDS) — reads the csr bgat1 exported in place of pairs.
__global__ __launch_bounds__(256) void gat2_k(
    const int* __restrict__ csr, const int2* __restrict__ rs_cnt,
    const float4* __restrict__ h2p, const float* __restrict__ adst2,
    const float* __restrict__ b2, float* __restrict__ out) {
    __shared__ float sB2[OUTC];
    int t = threadIdx.x;
    if (t < OUTC) sB2[t] = b2[t];
    __syncthreads();

    int node = (blockIdx.x * 256 + t) >> 4;   // grid exact: 6250*256/16 = 100000
    int lane = t & 15;
    int2 rc = rs_cnt[node];
    int start = rc.x, len = rc.y;
    float ad  = adst2[node];

    float acc[OUTC];
    #pragma unroll
    for (int c = 0; c < OUTC; ++c) acc[c] = 0.0f;
    float accd = 0.0f;
    int it = lane;
    for (; it + 16 < len; it += 32) {
        int s0 = csr[start + it];
        int s1 = csr[start + it + 16];
        float4 r0 = h2p[s0];
        float4 r1 = h2p[s1];
        float v0 = r0.x + ad;
        float v1 = r1.x + ad;
        v0 = (v0 > 0.0f) ? v0 : NEG_SLOPE * v0;
        v1 = (v1 > 0.0f) ? v1 : NEG_SLOPE * v1;
        float e0 = __expf(v0), e1 = __expf(v1);
        accd += e0 + e1;
        float2 a01 = unpk_half2(r0.y), a23 = unpk_half2(r0.z), a4 = unpk_half2(r0.w);
        float2 b01 = unpk_half2(r1.y), b23 = unpk_half2(r1.z), b4 = unpk_half2(r1.w);
        acc[0] += e0 * a01.x + e1 * b01.x;
        acc[1] += e0 * a01.y + e1 * b01.y;
        acc[2] += e0 * a23.x + e1 * b23.x;
        acc[3] += e0 * a23.y + e1 * b23.y;
        acc[4] += e0 * a4.x  + e1 * b4.x;
    }
    if (it < len) {
        int s = csr[start + it];
        float4 r = h2p[s];
        float v = r.x + ad;
        v = (v > 0.0f) ? v : NEG_SLOPE * v;
        float ex = __expf(v);
        accd += ex;
        float2 f01 = unpk_half2(r.y), f23 = unpk_half2(r.z), f4 = unpk_half2(r.w);
        acc[0] += ex * f01.x; acc[1] += ex * f01.y;
        acc[2] += ex * f23.x; acc[3] += ex * f23.y;
        acc[4] += ex * f4.x;
    }
    #pragma unroll
    for (int off = 8; off; off >>= 1) {
        accd += __shfl_xor(accd, off);
        #pragma unroll
        for (int c = 0; c < OUTC; ++c) acc[c] += __shfl_xor(acc[c], off);
    }
    if (lane == 0) {
        float inv = 1.0f / (accd + 1e-16f);
        float val[OUTC];
        float mx = -3.4e38f;
        #pragma unroll
        for (int c = 0; c < OUTC; ++c) {
            val[c] = acc[c] * inv + sB2[c];
            mx = fmaxf(mx, val[c]);
        }
        float se = 0.0f;
        #pragma unroll
        for (int c = 0; c < OUTC; ++c) se += __expf(val[c] - mx);
        float lse = logf(se) + mx;
        #pragma unroll
        for (int c = 0; c < OUTC; ++c)
            out[(size_t)node * OUTC + c] = val[c] - lse;
    }
}

extern "C" void kernel_launch(void* const* d_in, const int* in_sizes, int n_in,
                              void* d_out, int out_size, void* d_ws, size_t ws_size,
                              hipStream_t stream) {
    const float* x   = (const float*)d_in[0];
    const int*   ei  = (const int*)d_in[1];
    const float* W1  = (const float*)d_in[2];
    const float* as1 = (const float*)d_in[3];
    const float* ad1 = (const float*)d_in[4];
    const float* b1  = (const float*)d_in[5];
    const float* W2  = (const float*)d_in[6];
    const float* as2 = (const float*)d_in[7];
    const float* ad2 = (const float*)d_in[8];
    const float* b2  = (const float*)d_in[9];
    float* out = (float*)d_out;

    // workspace layout (bytes), ~22.4 MB:
    //  pairs  @0           782*5120*4 = 16,015,360  [bgat1 rewrites in place as csr]
    //  h1f    @16,015,360  3,200,000
    //  adst1  @19,215,360  400,000
    //  h2p    @19,615,360  1,600,000
    //  adst2  @21,215,360  400,000
    //  gcnt   @21,615,360  3,128
    //  rs_cnt @21,618,560  800,000
    char* wsb = (char*)d_ws;
    unsigned* pairs = (unsigned*)wsb;
    __half* h1f     = (__half*)(wsb + 16015360);
    float*  adst1   = (float*)(wsb + 19215360);
    float4* h2p     = (float4*)(wsb + 19615360);
    float*  adst2   = (float*)(wsb + 21215360);
    int*    gcnt    = (int*)(wsb + 21615360);
    int2*   rs_cnt  = (int2*)(wsb + 21618560);

    // ---- zero bucket totals ----
    hipMemsetAsync(gcnt, 0, NBKT * sizeof(int), stream);
    // ---- fused: edge partition (806 blocks) + layer-1 projection (1563 tiles) ----
    partproj_k<<<PART_TILES + PROJ_TILES, 256, 0, stream>>>(
        ei, gcnt, pairs, x, W1, ad1, h1f, adst1);
    // ---- layer-1: bin + aggregate + relu + proj2; exports sorted csr + rs_cnt ----
    bgat1_k<<<NBKT, 512, 0, stream>>>(pairs, gcnt, h1f, as1, adst1, b1,
                                      W2, as2, ad2, h2p, adst2, rs_cnt);
    // ---- layer-2: bin-free aggregate + log_softmax (full-occupancy grid) ----
    gat2_k<<<AGG_GRID, 256, 0, stream>>>((const int*)pairs, rs_cnt, h2p, adst2,
                                         b2, out);
}

// Round 15
// 214.881 us; speedup vs baseline: 1.1064x; 1.0186x over previous
//
#include <hip/hip_runtime.h>
#include <hip/hip_fp16.h>

#define N_NODES 100000
#define N_EDGES 3200000
#define E_TOT   (N_EDGES + N_NODES)   // 3.3M edges incl self-loops
#define IN_C 128
#define HID  16
#define OUTC 5
#define NEG_SLOPE 0.2f

#define NBKT 391        // buckets of 256 dsts: b = dst >> 8 (r5-proven write-combining)
#define CAP  9216       // per-bucket pairs capacity (mean 8440, +8.5 sigma)
#define P_TILE 8192     // 21 edges/bucket/tile -> full-line pairs writes
#define PART_TILES ((E_TOT + P_TILE - 1) / P_TILE)  // 403
#define NT 64                                        // nodes per projection tile
#define PROJ_TILES ((N_NODES + NT - 1) / NT)         // 1563
#define AGG_GRID ((N_NODES + 15) / 16)               // 6250 (gat2 grid)
#define XH 136          // sXh row stride in halves (272B rows, 2-way alias = free)
#define XPADW 132       // sWt row stride in floats

__device__ __forceinline__ float pk_half2(float a, float b) {
    __half2 h = __halves2half2(__float2half(a), __float2half(b));
    return *(float*)&h;
}
__device__ __forceinline__ float2 unpk_half2(float v) {
    return __half22float2(*(__half2*)&v);
}

// ============ fused: edge partition (blocks 0..402) + layer-1 projection ============
// Partition = r5-exact staged form (391 buckets, P_TILE 8192): WRITE_SIZE ~27MB.
__global__ __launch_bounds__(256) void partproj_k(
    const int* __restrict__ ei, int* __restrict__ gcnt, unsigned* __restrict__ pairs,
    const float* __restrict__ x, const float* __restrict__ W1,
    const float* __restrict__ att_d,
    __half* __restrict__ h1f, float* __restrict__ a_dst) {
    __shared__ __align__(16) char smem[52288];
    int t = threadIdx.x;
    if (blockIdx.x < PART_TILES) {
        unsigned* vbuf       = (unsigned*)smem;                  // 32768 B
        unsigned short* bbuf = (unsigned short*)(smem + 32768);  // 16384 B
        int* hist            = (int*)(smem + 49152);             //  1564 B
        int* cur             = (int*)(smem + 50716);             //  1564 B
        for (int i = t; i < NBKT; i += 256) hist[i] = 0;
        __syncthreads();
        int base = blockIdx.x * P_TILE;
        int lim = E_TOT - base; if (lim > P_TILE) lim = P_TILE;
        for (int i = t; i < lim; i += 256) {
            int e = base + i;
            int s, d;
            if (e < N_EDGES) { s = ei[e]; d = ei[N_EDGES + e]; }
            else             { s = e - N_EDGES; d = s; }
            int b = d >> 8;
            vbuf[i] = ((unsigned)s << 8) | (unsigned)(d & 255);
            bbuf[i] = (unsigned short)b;
            atomicAdd(&hist[b], 1);
        }
        __syncthreads();
        for (int i = t; i < NBKT; i += 256) {
            int h = hist[i];
            cur[i] = h ? atomicAdd(&gcnt[i], h) : 0;   // reserve [cur, cur+h)
        }
        __syncthreads();
        for (int i = t; i < lim; i += 256) {
            int b = bbuf[i];
            int p = atomicAdd(&cur[b], 1);
            if (p >= 0 && p < CAP) pairs[(size_t)b * CAP + p] = vbuf[i];
        }
    } else {
        __half* sXh = (__half*)smem;           // 64 x 136 halves = 17408 B
        float*  sWt = (float*)(smem + 17408);  // 16 x 132 floats =  8448 B
        int bid = blockIdx.x - PART_TILES;
        int node0 = bid * NT;
        for (int i = t; i < IN_C * HID; i += 256) {
            int k = i >> 4, c = i & 15;
            sWt[c * XPADW + k] = W1[i];
        }
        const float4* x4 = (const float4*)x;
        for (int i = t; i < NT * 32; i += 256) {     // 2048 float4
            int r = i >> 5, c4 = i & 31;
            int node = node0 + r;
            float4 v = make_float4(0.f, 0.f, 0.f, 0.f);
            if (node < N_NODES) v = x4[(size_t)node * 32 + c4];
            __half2 h01 = __halves2half2(__float2half(v.x), __float2half(v.y));
            __half2 h23 = __halves2half2(__float2half(v.z), __float2half(v.w));
            float2 pk;
            pk.x = *(float*)&h01;
            pk.y = *(float*)&h23;
            *(float2*)&sXh[r * XH + c4 * 4] = pk;
        }
        __syncthreads();
        int rp = t >> 3, cp = t & 7;                 // 32 row-pairs x 8 col-pairs
        const __half* xr0 = &sXh[(2 * rp)     * XH];
        const __half* xr1 = &sXh[(2 * rp + 1) * XH];
        const float*  wr0 = &sWt[(2 * cp)     * XPADW];
        const float*  wr1 = &sWt[(2 * cp + 1) * XPADW];
        float4 A00 = make_float4(0.f, 0.f, 0.f, 0.f);
        float4 A01 = A00, A10 = A00, A11 = A00;
        #pragma unroll 4
        for (int kk = 0; kk < 16; ++kk) {            // 8 k's per iteration
            float4 hx0 = *(const float4*)&xr0[kk * 8];
            float4 hx1 = *(const float4*)&xr1[kk * 8];
            float4 w0a = *(const float4*)&wr0[kk * 8];
            float4 w0b = *(const float4*)&wr0[kk * 8 + 4];
            float4 w1a = *(const float4*)&wr1[kk * 8];
            float4 w1b = *(const float4*)&wr1[kk * 8 + 4];
            float2 x00 = unpk_half2(hx0.x), x01 = unpk_half2(hx0.y);
            float2 x02 = unpk_half2(hx0.z), x03 = unpk_half2(hx0.w);
            float2 x10 = unpk_half2(hx1.x), x11 = unpk_half2(hx1.y);
            float2 x12 = unpk_half2(hx1.z), x13 = unpk_half2(hx1.w);
            A00.x += x00.x * w0a.x; A00.y += x00.y * w0a.y;
            A00.z += x01.x * w0a.z; A00.w += x01.y * w0a.w;
            A00.x += x02.x * w0b.x; A00.y += x02.y * w0b.y;
            A00.z += x03.x * w0b.z; A00.w += x03.y * w0b.w;
            A01.x += x00.x * w1a.x; A01.y += x00.y * w1a.y;
            A01.z += x01.x * w1a.z; A01.w += x01.y * w1a.w;
            A01.x += x02.x * w1b.x; A01.y += x02.y * w1b.y;
            A01.z += x03.x * w1b.z; A01.w += x03.y * w1b.w;
            A10.x += x10.x * w0a.x; A10.y += x10.y * w0a.y;
            A10.z += x11.x * w0a.z; A10.w += x11.y * w0a.w;
            A10.x += x12.x * w0b.x; A10.y += x12.y * w0b.y;
            A10.z += x13.x * w0b.z; A10.w += x13.y * w0b.w;
            A11.x += x10.x * w1a.x; A11.y += x10.y * w1a.y;
            A11.z += x11.x * w1a.z; A11.w += x11.y * w1a.w;
            A11.x += x12.x * w1b.x; A11.y += x12.y * w1b.y;
            A11.z += x13.x * w1b.z; A11.w += x13.y * w1b.w;
        }
        float h00 = A00.x + A00.y + A00.z + A00.w;   // node 2rp,   col 2cp
        float h01 = A01.x + A01.y + A01.z + A01.w;   // node 2rp,   col 2cp+1
        float h10 = A10.x + A10.y + A10.z + A10.w;   // node 2rp+1, col 2cp
        float h11 = A11.x + A11.y + A11.z + A11.w;   // node 2rp+1, col 2cp+1
        float ad0 = att_d[2 * cp], ad1 = att_d[2 * cp + 1];
        float pd0 = h00 * ad0 + h01 * ad1;
        float pd1 = h10 * ad0 + h11 * ad1;
        #pragma unroll
        for (int off = 1; off < 8; off <<= 1) {
            pd0 += __shfl_xor(pd0, off);
            pd1 += __shfl_xor(pd1, off);
        }
        int n0 = node0 + 2 * rp, n1 = n0 + 1;
        __half2* hp = (__half2*)h1f;
        if (n0 < N_NODES) {
            hp[(size_t)n0 * 8 + cp] = __halves2half2(__float2half(h00), __float2half(h01));
            if (cp == 0) a_dst[n0] = pd0;
        }
        if (n1 < N_NODES) {
            hp[(size_t)n1 * 8 + cp] = __halves2half2(__float2half(h10), __float2half(h11));
            if (cp == 0) a_dst[n1] = pd1;
        }
    }
}

// ======== bucket binning (256-dst, 1024 threads): hist + scan + scatter into lcsr ====
__device__ __forceinline__ int bin_bucket(int b, const unsigned* __restrict__ pairs,
        const int* __restrict__ gcnt, int* lcsr, int* ccnt, int* sexc, int* cur) {
    int t = threadIdx.x;
    if (t < 256) ccnt[t] = 0;
    __syncthreads();
    int tot = gcnt[b];
    if (tot > CAP) tot = CAP; if (tot < 0) tot = 0;
    size_t pb = (size_t)b * CAP;
    for (int i = t; i < tot; i += 1024)
        atomicAdd(&ccnt[pairs[pb + i] & 255u], 1);
    __syncthreads();
    if (t < 256) sexc[t] = ccnt[t];
    __syncthreads();
    for (int off = 1; off < 256; off <<= 1) {
        int xv = 0;
        if (t < 256 && t >= off) xv = sexc[t - off];
        __syncthreads();
        if (t < 256) sexc[t] += xv;
        __syncthreads();
    }
    if (t < 256) cur[t] = sexc[t] - ccnt[t];
    __syncthreads();
    for (int i = t; i < tot; i += 1024) {
        unsigned v = pairs[pb + i];
        int pos = atomicAdd(&cur[v & 255u], 1);
        if (pos >= 0 && pos < CAP) lcsr[pos] = (int)(v >> 8);   // defensive clamp
    }
    __syncthreads();
    return tot;
}

// ===== layer-1: bin + gather engine + epilogue; EXPORTS bins (in-place csr + rs_cnt)
// 1024 threads/block: 2 blocks/CU (thread-limited) -> 16-32 waves/CU latency hiding.
__global__ __launch_bounds__(1024) void bgat1_k(
    unsigned* __restrict__ pairs, const int* __restrict__ gcnt,
    const __half* __restrict__ h1f, const float* __restrict__ att_s1,
    const float* __restrict__ adst1, const float* __restrict__ b1,
    const float* __restrict__ W2, const float* __restrict__ as2,
    const float* __restrict__ ad2, float4* __restrict__ h2p,
    float* __restrict__ adst2, int2* __restrict__ rs_cnt) {
    __shared__ __align__(16) int lcsr[CAP];        // 36864 B
    __shared__ int ccnt[256], sexc[256], cur[256]; //  3072 B
    __shared__ __align__(16) float sW2t[OUTC][20]; //   400 B
    __shared__ __align__(16) float sG[64][16];     //  4096 B
    __shared__ __align__(16) float sH2[64][8];     //  2048 B
    __shared__ __align__(16) float sAsd[16];       //    64 B  (total ~46.5 KB)
    int t = threadIdx.x;
    int b = blockIdx.x;
    if (t < 16) sAsd[t] = 0.0f;
    if (t < HID * OUTC) sW2t[t % OUTC][t / OUTC] = W2[t];
    if (t < OUTC) { sAsd[t] = as2[t]; sAsd[8 + t] = ad2[t]; }
    int lane = t & 15;
    int sub  = lane & 1;        // half-row owner
    int eslot = lane >> 1;      // 8 edge slots
    int ch = sub * 8 + ((lane >> 1) & 1) * 4 + ((lane >> 2) & 1) * 2 + ((lane >> 3) & 1);
    float rB1 = b1[ch];
    float attr[8];
    #pragma unroll
    for (int j = 0; j < 8; ++j) attr[j] = att_s1[sub * 8 + j];

    int tot = bin_bucket(b, pairs, gcnt, lcsr, ccnt, sexc, cur);

    // ---- export bins: in-place sorted csr over this bucket's (now-dead) pairs
    //      region (linear coalesced store) + per-node (start,len) ----
    size_t pb = (size_t)b * CAP;
    for (int i = t; i < tot; i += 1024) pairs[pb + i] = (unsigned)lcsr[i];
    if (t < 256) {
        int node = (b << 8) + t;
        if (node < N_NODES) {
            int excl = sexc[t] - ccnt[t];
            int c = ccnt[t];
            if (excl < 0) excl = 0;                         // defensive
            if (excl + c > CAP) c = (excl < CAP) ? (CAP - excl) : 0;
            rs_cnt[node] = make_int2((int)pb + excl, c);
        }
    }

    int nl = t >> 4;            // 0..63: node group within pass
    for (int pass = 0; pass < 4; ++pass) {
        int nloc = pass * 64 + nl;           // 0..255
        int node = (b << 8) + nloc;
        int len = ccnt[nloc];
        int start = sexc[nloc] - len;
        if (start < 0) start = 0;                           // defensive
        if (start + len > CAP) len = (start < CAP) ? (CAP - start) : 0;
        float ad = (node < N_NODES) ? adst1[node] : 0.0f;

        float acc[8];
        #pragma unroll
        for (int c = 0; c < 8; ++c) acc[c] = 0.0f;
        float accd = 0.0f;
        int it = eslot;
        for (; it + 8 < len; it += 16) {
            int s0 = lcsr[start + it];
            int s1 = lcsr[start + it + 8];
            float4 p = *(const float4*)(h1f + (size_t)s0 * HID + sub * 8);
            float4 q = *(const float4*)(h1f + (size_t)s1 * HID + sub * 8);
            float2 f0 = unpk_half2(p.x), f1 = unpk_half2(p.y);
            float2 f2 = unpk_half2(p.z), f3 = unpk_half2(p.w);
            float2 g0 = unpk_half2(q.x), g1 = unpk_half2(q.y);
            float2 g2 = unpk_half2(q.z), g3 = unpk_half2(q.w);
            float pp0 = f0.x*attr[0] + f0.y*attr[1] + f1.x*attr[2] + f1.y*attr[3]
                      + f2.x*attr[4] + f2.y*attr[5] + f3.x*attr[6] + f3.y*attr[7];
            float pp1 = g0.x*attr[0] + g0.y*attr[1] + g1.x*attr[2] + g1.y*attr[3]
                      + g2.x*attr[4] + g2.y*attr[5] + g3.x*attr[6] + g3.y*attr[7];
            float v0 = pp0 + __shfl_xor(pp0, 1) + ad;
            float v1 = pp1 + __shfl_xor(pp1, 1) + ad;
            v0 = (v0 > 0.0f) ? v0 : NEG_SLOPE * v0;
            v1 = (v1 > 0.0f) ? v1 : NEG_SLOPE * v1;
            float e0 = __expf(v0), e1 = __expf(v1);
            accd += e0 + e1;
            acc[0] += e0 * f0.x + e1 * g0.x; acc[1] += e0 * f0.y + e1 * g0.y;
            acc[2] += e0 * f1.x + e1 * g1.x; acc[3] += e0 * f1.y + e1 * g1.y;
            acc[4] += e0 * f2.x + e1 * g2.x; acc[5] += e0 * f2.y + e1 * g2.y;
            acc[6] += e0 * f3.x + e1 * g3.x; acc[7] += e0 * f3.y + e1 * g3.y;
        }
        if (it < len) {
            int s = lcsr[start + it];
            float4 p = *(const float4*)(h1f + (size_t)s * HID + sub * 8);
            float2 f0 = unpk_half2(p.x), f1 = unpk_half2(p.y);
            float2 f2 = unpk_half2(p.z), f3 = unpk_half2(p.w);
            float pp = f0.x*attr[0] + f0.y*attr[1] + f1.x*attr[2] + f1.y*attr[3]
                     + f2.x*attr[4] + f2.y*attr[5] + f3.x*attr[6] + f3.y*attr[7];
            float v = pp + __shfl_xor(pp, 1) + ad;
            v = (v > 0.0f) ? v : NEG_SLOPE * v;
            float ex = __expf(v);
            accd += ex;
            acc[0] += ex * f0.x; acc[1] += ex * f0.y;
            acc[2] += ex * f1.x; acc[3] += ex * f1.y;
            acc[4] += ex * f2.x; acc[5] += ex * f2.y;
            acc[6] += ex * f3.x; acc[7] += ex * f3.y;
        }
        // halving butterfly across 8 edge-slots (xor 2,4,8): 7 shuffles
        {
            bool b2 = (lane & 2) != 0;
            #pragma unroll
            for (int c = 0; c < 4; ++c) {
                float send = b2 ? acc[c] : acc[c + 4];
                float r = __shfl_xor(send, 2);
                acc[c] = (b2 ? acc[c + 4] : acc[c]) + r;
            }
            bool b4 = (lane & 4) != 0;
            #pragma unroll
            for (int c = 0; c < 2; ++c) {
                float send = b4 ? acc[c] : acc[c + 2];
                float r = __shfl_xor(send, 4);
                acc[c] = (b4 ? acc[c + 2] : acc[c]) + r;
            }
            bool b8 = (lane & 8) != 0;
            {
                float send = b8 ? acc[0] : acc[1];
                float r = __shfl_xor(send, 8);
                acc[0] = (b8 ? acc[1] : acc[0]) + r;
            }
        }
        accd += __shfl_xor(accd, 2);
        accd += __shfl_xor(accd, 4);
        accd += __shfl_xor(accd, 8);

        float inv = 1.0f / (accd + 1e-16f);
        float g = fmaxf(acc[0] * inv + rB1, 0.0f);   // lane holds channel ch
        sG[nl][ch] = g;              // wave-local write/read: no sync needed
        if (lane < OUTC) {
            const float4* gp = (const float4*)sG[nl];
            const float4* wp = (const float4*)sW2t[lane];
            float h2v = 0.0f;
            #pragma unroll
            for (int k4 = 0; k4 < 4; ++k4) {
                float4 gv = gp[k4], wv = wp[k4];
                h2v += gv.x * wv.x + gv.y * wv.y + gv.z * wv.z + gv.w * wv.w;
            }
            sH2[nl][lane] = h2v;
            if (lane == 0 && node < N_NODES) {
                float4 hv = *(const float4*)&sH2[nl][0];
                float h24 = sH2[nl][4];
                float4 as4 = *(const float4*)&sAsd[0]; float as_4 = sAsd[4];
                float4 ad4 = *(const float4*)&sAsd[8]; float ad_4 = sAsd[12];
                float s2 = hv.x * as4.x + hv.y * as4.y + hv.z * as4.z + hv.w * as4.w + h24 * as_4;
                float d2 = hv.x * ad4.x + hv.y * ad4.y + hv.z * ad4.z + hv.w * ad4.w + h24 * ad_4;
                adst2[node] = d2;
                float4 r;
                r.x = s2;
                r.y = pk_half2(hv.x, hv.y);
                r.z = pk_half2(hv.z, hv.w);
                r.w = pk_half2(h24, 0.0f);
                h2p[node] = r;
            }
        }
    }
}

// ===== layer-2 aggregate (r5-verified engine): 16 lanes/node, unroll-2, full
// occupancy (no big LDS) — reads the csr bgat1 exported in place of pairs.
__global__ __launch_bounds__(256) void gat2_k(
    const int* __restrict__ csr, const int2* __restrict__ rs_cnt,
    const float4* __restrict__ h2p, const float* __restrict__ adst2,
    const float* __restrict__ b2, float* __restrict__ out) {
    __shared__ float sB2[OUTC];
    int t = threadIdx.x;
    if (t < OUTC) sB2[t] = b2[t];
    __syncthreads();

    int node = (blockIdx.x * 256 + t) >> 4;   // grid exact: 6250*256/16 = 100000
    int lane = t & 15;
    int2 rc = rs_cnt[node];
    int start = rc.x, len = rc.y;
    float ad  = adst2[node];

    float acc[OUTC];
    #pragma unroll
    for (int c = 0; c < OUTC; ++c) acc[c] = 0.0f;
    float accd = 0.0f;
    int it = lane;
    for (; it + 16 < len; it += 32) {
        int s0 = csr[start + it];
        int s1 = csr[start + it + 16];
        float4 r0 = h2p[s0];
        float4 r1 = h2p[s1];
        float v0 = r0.x + ad;
        float v1 = r1.x + ad;
        v0 = (v0 > 0.0f) ? v0 : NEG_SLOPE * v0;
        v1 = (v1 > 0.0f) ? v1 : NEG_SLOPE * v1;
        float e0 = __expf(v0), e1 = __expf(v1);
        accd += e0 + e1;
        float2 a01 = unpk_half2(r0.y), a23 = unpk_half2(r0.z), a4 = unpk_half2(r0.w);
        float2 b01 = unpk_half2(r1.y), b23 = unpk_half2(r1.z), b4 = unpk_half2(r1.w);
        acc[0] += e0 * a01.x + e1 * b01.x;
        acc[1] += e0 * a01.y + e1 * b01.y;
        acc[2] += e0 * a23.x + e1 * b23.x;
        acc[3] += e0 * a23.y + e1 * b23.y;
        acc[4] += e0 * a4.x  + e1 * b4.x;
    }
    if (it < len) {
        int s = csr[start + it];
        float4 r = h2p[s];
        float v = r.x + ad;
        v = (v > 0.0f) ? v : NEG_SLOPE * v;
        float ex = __expf(v);
        accd += ex;
        float2 f01 = unpk_half2(r.y), f23 = unpk_half2(r.z), f4 = unpk_half2(r.w);
        acc[0] += ex * f01.x; acc[1] += ex * f01.y;
        acc[2] += ex * f23.x; acc[3] += ex * f23.y;
        acc[4] += ex * f4.x;
    }
    #pragma unroll
    for (int off = 8; off; off >>= 1) {
        accd += __shfl_xor(accd, off);
        #pragma unroll
        for (int c = 0; c < OUTC; ++c) acc[c] += __shfl_xor(acc[c], off);
    }
    if (lane == 0) {
        float inv = 1.0f / (accd + 1e-16f);
        float val[OUTC];
        float mx = -3.4e38f;
        #pragma unroll
        for (int c = 0; c < OUTC; ++c) {
            val[c] = acc[c] * inv + sB2[c];
            mx = fmaxf(mx, val[c]);
        }
        float se = 0.0f;
        #pragma unroll
        for (int c = 0; c < OUTC; ++c) se += __expf(val[c] - mx);
        float lse = logf(se) + mx;
        #pragma unroll
        for (int c = 0; c < OUTC; ++c)
            out[(size_t)node * OUTC + c] = val[c] - lse;
    }
}

extern "C" void kernel_launch(void* const* d_in, const int* in_sizes, int n_in,
                              void* d_out, int out_size, void* d_ws, size_t ws_size,
                              hipStream_t stream) {
    const float* x   = (const float*)d_in[0];
    const int*   ei  = (const int*)d_in[1];
    const float* W1  = (const float*)d_in[2];
    const float* as1 = (const float*)d_in[3];
    const float* ad1 = (const float*)d_in[4];
    const float* b1  = (const float*)d_in[5];
    const float* W2  = (const float*)d_in[6];
    const float* as2 = (const float*)d_in[7];
    const float* ad2 = (const float*)d_in[8];
    const float* b2  = (const float*)d_in[9];
    float* out = (float*)d_out;

    // workspace layout (bytes), ~20.8 MB:
    //  pairs  @0           391*9216*4 = 14,413,824  [bgat1 rewrites in place as csr]
    //  h1f    @14,413,824  3,200,000
    //  adst1  @17,613,824  400,000
    //  h2p    @18,013,824  1,600,000
    //  adst2  @19,613,824  400,000
    //  gcnt   @20,013,824  1,564
    //  rs_cnt @20,016,000  800,000
    char* wsb = (char*)d_ws;
    unsigned* pairs = (unsigned*)wsb;
    __half* h1f     = (__half*)(wsb + 14413824);
    float*  adst1   = (float*)(wsb + 17613824);
    float4* h2p     = (float4*)(wsb + 18013824);
    float*  adst2   = (float*)(wsb + 19613824);
    int*    gcnt    = (int*)(wsb + 20013824);
    int2*   rs_cnt  = (int2*)(wsb + 20016000);

    // ---- zero bucket totals ----
    hipMemsetAsync(gcnt, 0, NBKT * sizeof(int), stream);
    // ---- fused: edge partition (403 blocks) + layer-1 projection (1563 tiles) ----
    partproj_k<<<PART_TILES + PROJ_TILES, 256, 0, stream>>>(
        ei, gcnt, pairs, x, W1, ad1, h1f, adst1);
    // ---- layer-1: bin + aggregate + relu + proj2; exports sorted csr + rs_cnt ----
    bgat1_k<<<NBKT, 1024, 0, stream>>>(pairs, gcnt, h1f, as1, adst1, b1,
                                       W2, as2, ad2, h2p, adst2, rs_cnt);
    // ---- layer-2: bin-free aggregate + log_softmax (full-occupancy grid) ----
    gat2_k<<<AGG_GRID, 256, 0, stream>>>((const int*)pairs, rs_cnt, h2p, adst2,
                                         b2, out);
}

// Round 16
// 208.523 us; speedup vs baseline: 1.1401x; 1.0305x over previous
//
#include <hip/hip_runtime.h>
#include <hip/hip_fp16.h>

#define N_NODES 100000
#define N_EDGES 3200000
#define E_TOT   (N_EDGES + N_NODES)   // 3.3M edges incl self-loops
#define IN_C 128
#define HID  16
#define OUTC 5
#define NEG_SLOPE 0.2f

#define NBKT 391        // buckets of 256 dsts: b = dst >> 8 (r5-proven write-combining)
#define CAP  9216       // per-bucket pairs capacity (mean 8440, +8.5 sigma)
#define P_TILE 8192     // 21 edges/bucket/tile -> full-line pairs writes
#define PART_TILES ((E_TOT + P_TILE - 1) / P_TILE)  // 403
#define NT 64                                        // nodes per projection tile
#define PROJ_TILES ((N_NODES + NT - 1) / NT)         // 1563
#define AGG2_GRID ((N_NODES + 31) / 32)              // 3125 (gat2: 8 lanes/node)
#define XH 136          // sXh row stride in halves (272B rows, 2-way alias = free)
#define XPADW 132       // sWt row stride in floats

__device__ __forceinline__ float pk_half2(float a, float b) {
    __half2 h = __halves2half2(__float2half(a), __float2half(b));
    return *(float*)&h;
}
__device__ __forceinline__ float2 unpk_half2(float v) {
    return __half22float2(*(__half2*)&v);
}

// ============ fused: edge partition (blocks 0..402) + layer-1 projection ============
// Partition = r5-exact staged form (391 buckets, P_TILE 8192): WRITE_SIZE ~27MB.
__global__ __launch_bounds__(256) void partproj_k(
    const int* __restrict__ ei, int* __restrict__ gcnt, unsigned* __restrict__ pairs,
    const float* __restrict__ x, const float* __restrict__ W1,
    const float* __restrict__ att_d,
    __half* __restrict__ h1f, float* __restrict__ a_dst) {
    __shared__ __align__(16) char smem[52288];
    int t = threadIdx.x;
    if (blockIdx.x < PART_TILES) {
        unsigned* vbuf       = (unsigned*)smem;                  // 32768 B
        unsigned short* bbuf = (unsigned short*)(smem + 32768);  // 16384 B
        int* hist            = (int*)(smem + 49152);             //  1564 B
        int* cur             = (int*)(smem + 50716);             //  1564 B
        for (int i = t; i < NBKT; i += 256) hist[i] = 0;
        __syncthreads();
        int base = blockIdx.x * P_TILE;
        int lim = E_TOT - base; if (lim > P_TILE) lim = P_TILE;
        for (int i = t; i < lim; i += 256) {
            int e = base + i;
            int s, d;
            if (e < N_EDGES) { s = ei[e]; d = ei[N_EDGES + e]; }
            else             { s = e - N_EDGES; d = s; }
            int b = d >> 8;
            vbuf[i] = ((unsigned)s << 8) | (unsigned)(d & 255);
            bbuf[i] = (unsigned short)b;
            atomicAdd(&hist[b], 1);
        }
        __syncthreads();
        for (int i = t; i < NBKT; i += 256) {
            int h = hist[i];
            cur[i] = h ? atomicAdd(&gcnt[i], h) : 0;   // reserve [cur, cur+h)
        }
        __syncthreads();
        for (int i = t; i < lim; i += 256) {
            int b = bbuf[i];
            int p = atomicAdd(&cur[b], 1);
            if (p >= 0 && p < CAP) pairs[(size_t)b * CAP + p] = vbuf[i];
        }
    } else {
        __half* sXh = (__half*)smem;           // 64 x 136 halves = 17408 B
        float*  sWt = (float*)(smem + 17408);  // 16 x 132 floats =  8448 B
        int bid = blockIdx.x - PART_TILES;
        int node0 = bid * NT;
        for (int i = t; i < IN_C * HID; i += 256) {
            int k = i >> 4, c = i & 15;
            sWt[c * XPADW + k] = W1[i];
        }
        const float4* x4 = (const float4*)x;
        for (int i = t; i < NT * 32; i += 256) {     // 2048 float4
            int r = i >> 5, c4 = i & 31;
            int node = node0 + r;
            float4 v = make_float4(0.f, 0.f, 0.f, 0.f);
            if (node < N_NODES) v = x4[(size_t)node * 32 + c4];
            __half2 h01 = __halves2half2(__float2half(v.x), __float2half(v.y));
            __half2 h23 = __halves2half2(__float2half(v.z), __float2half(v.w));
            float2 pk;
            pk.x = *(float*)&h01;
            pk.y = *(float*)&h23;
            *(float2*)&sXh[r * XH + c4 * 4] = pk;
        }
        __syncthreads();
        int rp = t >> 3, cp = t & 7;                 // 32 row-pairs x 8 col-pairs
        const __half* xr0 = &sXh[(2 * rp)     * XH];
        const __half* xr1 = &sXh[(2 * rp + 1) * XH];
        const float*  wr0 = &sWt[(2 * cp)     * XPADW];
        const float*  wr1 = &sWt[(2 * cp + 1) * XPADW];
        float4 A00 = make_float4(0.f, 0.f, 0.f, 0.f);
        float4 A01 = A00, A10 = A00, A11 = A00;
        #pragma unroll 4
        for (int kk = 0; kk < 16; ++kk) {            // 8 k's per iteration
            float4 hx0 = *(const float4*)&xr0[kk * 8];
            float4 hx1 = *(const float4*)&xr1[kk * 8];
            float4 w0a = *(const float4*)&wr0[kk * 8];
            float4 w0b = *(const float4*)&wr0[kk * 8 + 4];
            float4 w1a = *(const float4*)&wr1[kk * 8];
            float4 w1b = *(const float4*)&wr1[kk * 8 + 4];
            float2 x00 = unpk_half2(hx0.x), x01 = unpk_half2(hx0.y);
            float2 x02 = unpk_half2(hx0.z), x03 = unpk_half2(hx0.w);
            float2 x10 = unpk_half2(hx1.x), x11 = unpk_half2(hx1.y);
            float2 x12 = unpk_half2(hx1.z), x13 = unpk_half2(hx1.w);
            A00.x += x00.x * w0a.x; A00.y += x00.y * w0a.y;
            A00.z += x01.x * w0a.z; A00.w += x01.y * w0a.w;
            A00.x += x02.x * w0b.x; A00.y += x02.y * w0b.y;
            A00.z += x03.x * w0b.z; A00.w += x03.y * w0b.w;
            A01.x += x00.x * w1a.x; A01.y += x00.y * w1a.y;
            A01.z += x01.x * w1a.z; A01.w += x01.y * w1a.w;
            A01.x += x02.x * w1b.x; A01.y += x02.y * w1b.y;
            A01.z += x03.x * w1b.z; A01.w += x03.y * w1b.w;
            A10.x += x10.x * w0a.x; A10.y += x10.y * w0a.y;
            A10.z += x11.x * w0a.z; A10.w += x11.y * w0a.w;
            A10.x += x12.x * w0b.x; A10.y += x12.y * w0b.y;
            A10.z += x13.x * w0b.z; A10.w += x13.y * w0b.w;
            A11.x += x10.x * w1a.x; A11.y += x10.y * w1a.y;
            A11.z += x11.x * w1a.z; A11.w += x11.y * w1a.w;
            A11.x += x12.x * w1b.x; A11.y += x12.y * w1b.y;
            A11.z += x13.x * w1b.z; A11.w += x13.y * w1b.w;
        }
        float h00 = A00.x + A00.y + A00.z + A00.w;   // node 2rp,   col 2cp
        float h01 = A01.x + A01.y + A01.z + A01.w;   // node 2rp,   col 2cp+1
        float h10 = A10.x + A10.y + A10.z + A10.w;   // node 2rp+1, col 2cp
        float h11 = A11.x + A11.y + A11.z + A11.w;   // node 2rp+1, col 2cp+1
        float ad0 = att_d[2 * cp], ad1 = att_d[2 * cp + 1];
        float pd0 = h00 * ad0 + h01 * ad1;
        float pd1 = h10 * ad0 + h11 * ad1;
        #pragma unroll
        for (int off = 1; off < 8; off <<= 1) {
            pd0 += __shfl_xor(pd0, off);
            pd1 += __shfl_xor(pd1, off);
        }
        int n0 = node0 + 2 * rp, n1 = n0 + 1;
        __half2* hp = (__half2*)h1f;
        if (n0 < N_NODES) {
            hp[(size_t)n0 * 8 + cp] = __halves2half2(__float2half(h00), __float2half(h01));
            if (cp == 0) a_dst[n0] = pd0;
        }
        if (n1 < N_NODES) {
            hp[(size_t)n1 * 8 + cp] = __halves2half2(__float2half(h10), __float2half(h11));
            if (cp == 0) a_dst[n1] = pd1;
        }
    }
}

// ======== bucket binning (256-dst, 1024 threads): hist + WAVE-SCAN + scatter ========
// Scan via __shfl_up within 4 waves + segment fix-up: 5 barriers instead of ~18
// (barriers over 16-wave blocks are the bin phase's hidden cost).
__device__ __forceinline__ int bin_bucket(int b, const unsigned* __restrict__ pairs,
        const int* __restrict__ gcnt, int* lcsr, int* ccnt, int* sexc, int* cur,
        int* stot) {
    int t = threadIdx.x;
    if (t < 256) ccnt[t] = 0;
    __syncthreads();
    int tot = gcnt[b];
    if (tot > CAP) tot = CAP; if (tot < 0) tot = 0;
    size_t pb = (size_t)b * CAP;
    for (int i = t; i < tot; i += 1024)
        atomicAdd(&ccnt[pairs[pb + i] & 255u], 1);
    __syncthreads();
    // wave-level inclusive scan: wave w (0..3) scans ccnt[w*64 .. w*64+63]
    int wv = t >> 6, ln = t & 63;
    if (wv < 4) {
        int v = ccnt[wv * 64 + ln];
        #pragma unroll
        for (int off = 1; off < 64; off <<= 1) {
            int n = __shfl_up(v, off);
            if (ln >= off) v += n;
        }
        sexc[wv * 64 + ln] = v;      // inclusive within segment
    }
    __syncthreads();
    if (t < 4) stot[t] = sexc[t * 64 + 63];
    __syncthreads();
    if (wv < 4) {
        int segoff = 0;
        #pragma unroll
        for (int s = 0; s < 4; ++s) if (s < wv) segoff += stot[s];
        int idx = wv * 64 + ln;
        int inc = sexc[idx] + segoff;     // global inclusive
        sexc[idx] = inc;
        cur[idx] = inc - ccnt[idx];       // exclusive start
    }
    __syncthreads();
    for (int i = t; i < tot; i += 1024) {
        unsigned v = pairs[pb + i];
        int pos = atomicAdd(&cur[v & 255u], 1);
        if (pos >= 0 && pos < CAP) lcsr[pos] = (int)(v >> 8);   // defensive clamp
    }
    __syncthreads();
    return tot;
}

// ===== layer-1: bin + gather engine + epilogue; EXPORTS bins (in-place csr + rs_cnt)
// 1024 threads/block: 2 blocks/CU (thread-limited) -> 16-32 waves/CU latency hiding.
__global__ __launch_bounds__(1024) void bgat1_k(
    unsigned* __restrict__ pairs, const int* __restrict__ gcnt,
    const __half* __restrict__ h1f, const float* __restrict__ att_s1,
    const float* __restrict__ adst1, const float* __restrict__ b1,
    const float* __restrict__ W2, const float* __restrict__ as2,
    const float* __restrict__ ad2, float4* __restrict__ h2p,
    float* __restrict__ adst2, int2* __restrict__ rs_cnt) {
    __shared__ __align__(16) int lcsr[CAP];        // 36864 B
    __shared__ int ccnt[256], sexc[256], cur[256]; //  3072 B
    __shared__ int stot[4];
    __shared__ __align__(16) float sW2t[OUTC][20]; //   400 B
    __shared__ __align__(16) float sG[64][16];     //  4096 B
    __shared__ __align__(16) float sH2[64][8];     //  2048 B
    __shared__ __align__(16) float sAsd[16];       //    64 B  (total ~46.6 KB)
    int t = threadIdx.x;
    int b = blockIdx.x;
    if (t < 16) sAsd[t] = 0.0f;
    if (t < HID * OUTC) sW2t[t % OUTC][t / OUTC] = W2[t];
    if (t < OUTC) { sAsd[t] = as2[t]; sAsd[8 + t] = ad2[t]; }
    int lane = t & 15;
    int sub  = lane & 1;        // half-row owner
    int eslot = lane >> 1;      // 8 edge slots
    int ch = sub * 8 + ((lane >> 1) & 1) * 4 + ((lane >> 2) & 1) * 2 + ((lane >> 3) & 1);
    float rB1 = b1[ch];
    float attr[8];
    #pragma unroll
    for (int j = 0; j < 8; ++j) attr[j] = att_s1[sub * 8 + j];

    int tot = bin_bucket(b, pairs, gcnt, lcsr, ccnt, sexc, cur, stot);

    // ---- export bins: in-place sorted csr over this bucket's (now-dead) pairs
    //      region (linear coalesced store) + per-node (start,len) ----
    size_t pb = (size_t)b * CAP;
    for (int i = t; i < tot; i += 1024) pairs[pb + i] = (unsigned)lcsr[i];
    if (t < 256) {
        int node = (b << 8) + t;
        if (node < N_NODES) {
            int excl = sexc[t] - ccnt[t];
            int c = ccnt[t];
            if (excl < 0) excl = 0;                         // defensive
            if (excl + c > CAP) c = (excl < CAP) ? (CAP - excl) : 0;
            rs_cnt[node] = make_int2((int)pb + excl, c);
        }
    }

    int nl = t >> 4;            // 0..63: node group within pass
    for (int pass = 0; pass < 4; ++pass) {
        int nloc = pass * 64 + nl;           // 0..255
        int node = (b << 8) + nloc;
        int len = ccnt[nloc];
        int start = sexc[nloc] - len;
        if (start < 0) start = 0;                           // defensive
        if (start + len > CAP) len = (start < CAP) ? (CAP - start) : 0;
        float ad = (node < N_NODES) ? adst1[node] : 0.0f;

        float acc[8];
        #pragma unroll
        for (int c = 0; c < 8; ++c) acc[c] = 0.0f;
        float accd = 0.0f;
        int it = eslot;
        for (; it + 8 < len; it += 16) {
            int s0 = lcsr[start + it];
            int s1 = lcsr[start + it + 8];
            float4 p = *(const float4*)(h1f + (size_t)s0 * HID + sub * 8);
            float4 q = *(const float4*)(h1f + (size_t)s1 * HID + sub * 8);
            float2 f0 = unpk_half2(p.x), f1 = unpk_half2(p.y);
            float2 f2 = unpk_half2(p.z), f3 = unpk_half2(p.w);
            float2 g0 = unpk_half2(q.x), g1 = unpk_half2(q.y);
            float2 g2 = unpk_half2(q.z), g3 = unpk_half2(q.w);
            float pp0 = f0.x*attr[0] + f0.y*attr[1] + f1.x*attr[2] + f1.y*attr[3]
                      + f2.x*attr[4] + f2.y*attr[5] + f3.x*attr[6] + f3.y*attr[7];
            float pp1 = g0.x*attr[0] + g0.y*attr[1] + g1.x*attr[2] + g1.y*attr[3]
                      + g2.x*attr[4] + g2.y*attr[5] + g3.x*attr[6] + g3.y*attr[7];
            float v0 = pp0 + __shfl_xor(pp0, 1) + ad;
            float v1 = pp1 + __shfl_xor(pp1, 1) + ad;
            v0 = (v0 > 0.0f) ? v0 : NEG_SLOPE * v0;
            v1 = (v1 > 0.0f) ? v1 : NEG_SLOPE * v1;
            float e0 = __expf(v0), e1 = __expf(v1);
            accd += e0 + e1;
            acc[0] += e0 * f0.x + e1 * g0.x; acc[1] += e0 * f0.y + e1 * g0.y;
            acc[2] += e0 * f1.x + e1 * g1.x; acc[3] += e0 * f1.y + e1 * g1.y;
            acc[4] += e0 * f2.x + e1 * g2.x; acc[5] += e0 * f2.y + e1 * g2.y;
            acc[6] += e0 * f3.x + e1 * g3.x; acc[7] += e0 * f3.y + e1 * g3.y;
        }
        if (it < len) {
            int s = lcsr[start + it];
            float4 p = *(const float4*)(h1f + (size_t)s * HID + sub * 8);
            float2 f0 = unpk_half2(p.x), f1 = unpk_half2(p.y);
            float2 f2 = unpk_half2(p.z), f3 = unpk_half2(p.w);
            float pp = f0.x*attr[0] + f0.y*attr[1] + f1.x*attr[2] + f1.y*attr[3]
                     + f2.x*attr[4] + f2.y*attr[5] + f3.x*attr[6] + f3.y*attr[7];
            float v = pp + __shfl_xor(pp, 1) + ad;
            v = (v > 0.0f) ? v : NEG_SLOPE * v;
            float ex = __expf(v);
            accd += ex;
            acc[0] += ex * f0.x; acc[1] += ex * f0.y;
            acc[2] += ex * f1.x; acc[3] += ex * f1.y;
            acc[4] += ex * f2.x; acc[5] += ex * f2.y;
            acc[6] += ex * f3.x; acc[7] += ex * f3.y;
        }
        // halving butterfly across 8 edge-slots (xor 2,4,8): 7 shuffles
        {
            bool b2 = (lane & 2) != 0;
            #pragma unroll
            for (int c = 0; c < 4; ++c) {
                float send = b2 ? acc[c] : acc[c + 4];
                float r = __shfl_xor(send, 2);
                acc[c] = (b2 ? acc[c + 4] : acc[c]) + r;
            }
            bool b4 = (lane & 4) != 0;
            #pragma unroll
            for (int c = 0; c < 2; ++c) {
                float send = b4 ? acc[c] : acc[c + 2];
                float r = __shfl_xor(send, 4);
                acc[c] = (b4 ? acc[c + 2] : acc[c]) + r;
            }
            bool b8 = (lane & 8) != 0;
            {
                float send = b8 ? acc[0] : acc[1];
                float r = __shfl_xor(send, 8);
                acc[0] = (b8 ? acc[1] : acc[0]) + r;
            }
        }
        accd += __shfl_xor(accd, 2);
        accd += __shfl_xor(accd, 4);
        accd += __shfl_xor(accd, 8);

        float inv = 1.0f / (accd + 1e-16f);
        float g = fmaxf(acc[0] * inv + rB1, 0.0f);   // lane holds channel ch
        sG[nl][ch] = g;              // wave-local write/read: no sync needed
        if (lane < OUTC) {
            const float4* gp = (const float4*)sG[nl];
            const float4* wp = (const float4*)sW2t[lane];
            float h2v = 0.0f;
            #pragma unroll
            for (int k4 = 0; k4 < 4; ++k4) {
                float4 gv = gp[k4], wv = wp[k4];
                h2v += gv.x * wv.x + gv.y * wv.y + gv.z * wv.z + gv.w * wv.w;
            }
            sH2[nl][lane] = h2v;
            if (lane == 0 && node < N_NODES) {
                float4 hv = *(const float4*)&sH2[nl][0];
                float h24 = sH2[nl][4];
                float4 as4 = *(const float4*)&sAsd[0]; float as_4 = sAsd[4];
                float4 ad4 = *(const float4*)&sAsd[8]; float ad_4 = sAsd[12];
                float s2 = hv.x * as4.x + hv.y * as4.y + hv.z * as4.z + hv.w * as4.w + h24 * as_4;
                float d2 = hv.x * ad4.x + hv.y * ad4.y + hv.z * ad4.z + hv.w * ad4.w + h24 * ad_4;
                adst2[node] = d2;
                float4 r;
                r.x = s2;
                r.y = pk_half2(hv.x, hv.y);
                r.z = pk_half2(hv.z, hv.w);
                r.w = pk_half2(h24, 0.0f);
                h2p[node] = r;
            }
        }
    }
}

// ===== layer-2 aggregate: 8 lanes/node (mean degree 33 -> 4.1 edges/lane; halves
// per-node fixed cost vs 16-lane), unroll-2, full occupancy.
__global__ __launch_bounds__(256) void gat2_k(
    const int* __restrict__ csr, const int2* __restrict__ rs_cnt,
    const float4* __restrict__ h2p, const float* __restrict__ adst2,
    const float* __restrict__ b2, float* __restrict__ out) {
    __shared__ float sB2[OUTC];
    int t = threadIdx.x;
    if (t < OUTC) sB2[t] = b2[t];
    __syncthreads();

    int node = (blockIdx.x * 256 + t) >> 3;   // grid exact: 3125*256/8 = 100000
    int lane = t & 7;
    int2 rc = rs_cnt[node];
    int start = rc.x, len = rc.y;
    float ad  = adst2[node];

    float acc[OUTC];
    #pragma unroll
    for (int c = 0; c < OUTC; ++c) acc[c] = 0.0f;
    float accd = 0.0f;
    int it = lane;
    for (; it + 8 < len; it += 16) {
        int s0 = csr[start + it];
        int s1 = csr[start + it + 8];
        float4 r0 = h2p[s0];
        float4 r1 = h2p[s1];
        float v0 = r0.x + ad;
        float v1 = r1.x + ad;
        v0 = (v0 > 0.0f) ? v0 : NEG_SLOPE * v0;
        v1 = (v1 > 0.0f) ? v1 : NEG_SLOPE * v1;
        float e0 = __expf(v0), e1 = __expf(v1);
        accd += e0 + e1;
        float2 a01 = unpk_half2(r0.y), a23 = unpk_half2(r0.z), a4 = unpk_half2(r0.w);
        float2 b01 = unpk_half2(r1.y), b23 = unpk_half2(r1.z), b4 = unpk_half2(r1.w);
        acc[0] += e0 * a01.x + e1 * b01.x;
        acc[1] += e0 * a01.y + e1 * b01.y;
        acc[2] += e0 * a23.x + e1 * b23.x;
        acc[3] += e0 * a23.y + e1 * b23.y;
        acc[4] += e0 * a4.x  + e1 * b4.x;
    }
    if (it < len) {
        int s = csr[start + it];
        float4 r = h2p[s];
        float v = r.x + ad;
        v = (v > 0.0f) ? v : NEG_SLOPE * v;
        float ex = __expf(v);
        accd += ex;
        float2 f01 = unpk_half2(r.y), f23 = unpk_half2(r.z), f4 = unpk_half2(r.w);
        acc[0] += ex * f01.x; acc[1] += ex * f01.y;
        acc[2] += ex * f23.x; acc[3] += ex * f23.y;
        acc[4] += ex * f4.x;
    }
    #pragma unroll
    for (int off = 4; off; off >>= 1) {
        accd += __shfl_xor(accd, off);
        #pragma unroll
        for (int c = 0; c < OUTC; ++c) acc[c] += __shfl_xor(acc[c], off);
    }
    if (lane == 0) {
        float inv = 1.0f / (accd + 1e-16f);
        float val[OUTC];
        float mx = -3.4e38f;
        #pragma unroll
        for (int c = 0; c < OUTC; ++c) {
            val[c] = acc[c] * inv + sB2[c];
            mx = fmaxf(mx, val[c]);
        }
        float se = 0.0f;
        #pragma unroll
        for (int c = 0; c < OUTC; ++c) se += __expf(val[c] - mx);
        float lse = logf(se) + mx;
        #pragma unroll
        for (int c = 0; c < OUTC; ++c)
            out[(size_t)node * OUTC + c] = val[c] - lse;
    }
}

extern "C" void kernel_launch(void* const* d_in, const int* in_sizes, int n_in,
                              void* d_out, int out_size, void* d_ws, size_t ws_size,
                              hipStream_t stream) {
    const float* x   = (const float*)d_in[0];
    const int*   ei  = (const int*)d_in[1];
    const float* W1  = (const float*)d_in[2];
    const float* as1 = (const float*)d_in[3];
    const float* ad1 = (const float*)d_in[4];
    const float* b1  = (const float*)d_in[5];
    const float* W2  = (const float*)d_in[6];
    const float* as2 = (const float*)d_in[7];
    const float* ad2 = (const float*)d_in[8];
    const float* b2  = (const float*)d_in[9];
    float* out = (float*)d_out;

    // workspace layout (bytes), ~20.8 MB:
    //  pairs  @0           391*9216*4 = 14,413,824  [bgat1 rewrites in place as csr]
    //  h1f    @14,413,824  3,200,000
    //  adst1  @17,613,824  400,000
    //  h2p    @18,013,824  1,600,000
    //  adst2  @19,613,824  400,000
    //  gcnt   @20,013,824  1,564
    //  rs_cnt @20,016,000  800,000
    char* wsb = (char*)d_ws;
    unsigned* pairs = (unsigned*)wsb;
    __half* h1f     = (__half*)(wsb + 14413824);
    float*  adst1   = (float*)(wsb + 17613824);
    float4* h2p     = (float4*)(wsb + 18013824);
    float*  adst2   = (float*)(wsb + 19613824);
    int*    gcnt    = (int*)(wsb + 20013824);
    int2*   rs_cnt  = (int2*)(wsb + 20016000);

    // ---- zero bucket totals ----
    hipMemsetAsync(gcnt, 0, NBKT * sizeof(int), stream);
    // ---- fused: edge partition (403 blocks) + layer-1 projection (1563 tiles) ----
    partproj_k<<<PART_TILES + PROJ_TILES, 256, 0, stream>>>(
        ei, gcnt, pairs, x, W1, ad1, h1f, adst1);
    // ---- layer-1: bin + aggregate + relu + proj2; exports sorted csr + rs_cnt ----
    bgat1_k<<<NBKT, 1024, 0, stream>>>(pairs, gcnt, h1f, as1, adst1, b1,
                                       W2, as2, ad2, h2p, adst2, rs_cnt);
    // ---- layer-2: bin-free aggregate + log_softmax (8 lanes/node, 3125 blocks) ----
    gat2_k<<<AGG2_GRID, 256, 0, stream>>>((const int*)pairs, rs_cnt, h2p, adst2,
                                          b2, out);
}